// Round 18
// baseline (737.555 us; speedup 1.0000x reference)
//
#include <hip/hip_runtime.h>
#include <hip/hip_bf16.h>
#include <stdint.h>

// ---------- types ----------
typedef __attribute__((ext_vector_type(4))) float f32x4;
typedef __attribute__((ext_vector_type(8))) __bf16 bf16x8;
typedef __attribute__((ext_vector_type(8))) unsigned short u16x8;
typedef __attribute__((ext_vector_type(4))) unsigned short u16x4;
typedef __attribute__((ext_vector_type(4))) unsigned int u32x4;

// global_load_lds, 16B per lane. LDS dest must be wave-uniform (HW adds lane*16).
#define GLL16(g, l) __builtin_amdgcn_global_load_lds( \
    (const __attribute__((address_space(1))) unsigned int*)(uintptr_t)(g), \
    (__attribute__((address_space(3))) unsigned int*)(uintptr_t)(l), 16, 0, 0)

__device__ __forceinline__ unsigned short bf16u(float f) {
  return __builtin_bit_cast(unsigned short, __float2bfloat16(f));
}

// ---------- problem constants ----------
#define PB 2
#define PS 2048
#define PNH 32
#define PHD 128
#define PH 4096
#define P3H 12288

// ---------- fp32 -> bf16 convert (vectorized, grid-stride) ----------
__global__ __launch_bounds__(256)
void cvt_f32_bf16(const float* __restrict__ in, unsigned short* __restrict__ out, int n) {
  int stride = gridDim.x * blockDim.x;
  for (int i = blockIdx.x * blockDim.x + threadIdx.x; i * 8 < n; i += stride) {
    int base = i * 8;
    f32x4 a = *(const f32x4*)(in + base);
    f32x4 b = *(const f32x4*)(in + base + 4);
    u16x8 o;
#pragma unroll
    for (int j = 0; j < 4; ++j) { o[j] = bf16u(a[j]); o[4 + j] = bf16u(b[j]); }
    *(u16x8*)(out + base) = o;
  }
}

// ---------- transpose + convert: in[K][N] f32 -> out[N][K] bf16 ----------
__global__ __launch_bounds__(256)
void transpose_cvt(const float* __restrict__ in, unsigned short* __restrict__ out,
                   int K, int N) {
  __shared__ __align__(16) unsigned short tile[64][68];
  int k0 = blockIdx.y * 64, n0 = blockIdx.x * 64;
  int t = threadIdx.x;
  int rr = t >> 4, cc = (t & 15) * 4;
#pragma unroll
  for (int p = 0; p < 4; ++p) {
    int r = rr + p * 16;
    f32x4 v = *(const f32x4*)(in + (size_t)(k0 + r) * N + n0 + cc);
    u16x4 w;
#pragma unroll
    for (int j = 0; j < 4; ++j) w[j] = bf16u(v[j]);
    *(u16x4*)&tile[r][cc] = w;
  }
  __syncthreads();
#pragma unroll
  for (int p = 0; p < 4; ++p) {
    int nl = rr + p * 16;
    u16x4 w;
#pragma unroll
    for (int j = 0; j < 4; ++j) w[j] = tile[cc + j][nl];
    *(u16x4*)(out + (size_t)(n0 + nl) * K + k0 + cc) = w;
  }
}

// ================= GEMM body 1: R14-proven (for GEMM1) =================
// 512 thr / 8 waves, BK=32, 4 LDS buffers, ping-pong A-frags + SGB
// interleave, counted vmcnt(4), bn-major XCD chunking. 343us/58% on GEMM1.
#define GLLP(TT, P) do { int sb_ = ((TT) & 3) << 15; \
    const unsigned short* s_ = (P) == 0 ? aSrc0 : (P) == 1 ? aSrc1 : (P) == 2 ? bSrc0 : bSrc1; \
    GLL16(s_ + (size_t)(TT) * 32, smem + sb_ + ((P) << 13) + (wave << 10)); } while (0)

#define RD_AV(DST, BUFP, I) DST[I] = *(const bf16x8*)((BUFP) + (((wm << 7) + ((I) << 4) + lr) << 6) + lchunk)
#define RD_BV(DST, BUFP, J) DST[J] = *(const bf16x8*)((BUFP) + 16384 + (((wn << 6) + ((J) << 4) + lr) << 6) + lchunk)

#define SGB __builtin_amdgcn_sched_group_barrier

#define TILE(TC, AC, AN, DOSTAGE, DOREAD, VM, DOBAR) do { \
    char* nA_ = smem + ((((TC) + 1) & 3) << 15); \
    __builtin_amdgcn_s_setprio(1); \
    _Pragma("unroll") \
    for (int g = 0; g < 4; ++g) { \
      if (DOREAD) { RD_AV(AN, nA_, 2 * g); RD_AV(AN, nA_, 2 * g + 1); } \
      if (DOSTAGE) GLLP((TC) + 3, g); \
      _Pragma("unroll") \
      for (int i = 2 * g; i < 2 * g + 2; ++i) \
        _Pragma("unroll") \
        for (int j = 0; j < 4; ++j) \
          acc[i][j] = __builtin_amdgcn_mfma_f32_16x16x32_bf16(AC[i], bvv[j], acc[i][j], 0, 0, 0); \
      SGB(0x100, 2, 0); SGB(0x020, 1, 0); SGB(0x008, 8, 0); \
    } \
    if (DOREAD) { RD_BV(bvv, nA_, 0); RD_BV(bvv, nA_, 1); RD_BV(bvv, nA_, 2); RD_BV(bvv, nA_, 3); } \
    __builtin_amdgcn_s_setprio(0); \
    if ((VM) == 4)      asm volatile("s_waitcnt vmcnt(4)" ::: "memory"); \
    else if ((VM) == 0) asm volatile("s_waitcnt vmcnt(0)" ::: "memory"); \
    if (DOBAR) __builtin_amdgcn_s_barrier(); \
  } while (0)

template<int OUTF32>
__global__ __launch_bounds__(512, 2)
void gemm_r14(const unsigned short* __restrict__ A, const unsigned short* __restrict__ Bt,
              void* __restrict__ Cv, int M, int N, int K) {
  __shared__ __align__(16) char smem[131072];
  const int tid = threadIdx.x;
  const int wave = tid >> 6, lane = tid & 63;
  const int lr = lane & 15, lg = lane >> 4;
  const int wm = wave >> 2, wn = wave & 3;
  const int lchunk = (lg ^ ((lr >> 1) & 3)) << 4;
  const int nbn = N >> 8;
  const int nbm = M >> 8;
  int bid = blockIdx.x;
  const int bnx = nbn >> 3;
  int x = bid & 7;
  int l = bid >> 3;
  int bm = l % nbm;
  int bn = x * bnx + l / nbm;
  const size_t arow = (size_t)bm << 8;
  const size_t brow = (size_t)bn << 8;

  const int srow = (wave << 4) + (lane >> 2);
  const int scol = ((lane & 3) ^ ((lane >> 3) & 3)) << 3;
  const unsigned short* aSrc0 = A  + (arow + srow) * K + scol;
  const unsigned short* aSrc1 = A  + (arow + 128 + srow) * K + scol;
  const unsigned short* bSrc0 = Bt + (brow + srow) * K + scol;
  const unsigned short* bSrc1 = Bt + (brow + 128 + srow) * K + scol;

  f32x4 acc[8][4] = {};

#pragma unroll
  for (int p = 0; p < 4; ++p) GLLP(0, p);
#pragma unroll
  for (int p = 0; p < 4; ++p) GLLP(1, p);
#pragma unroll
  for (int p = 0; p < 4; ++p) GLLP(2, p);
  asm volatile("s_waitcnt vmcnt(4)" ::: "memory");
  __builtin_amdgcn_s_barrier();

  bf16x8 avA[8], avB[8], bvv[4];
  {
    char* b0 = smem;
#pragma unroll
    for (int i = 0; i < 8; ++i) RD_AV(avA, b0, i);
#pragma unroll
    for (int j = 0; j < 4; ++j) RD_BV(bvv, b0, j);
  }

  for (int p = 0; p < 62; ++p) {
    int t = 2 * p;
    TILE(t,     avA, avB, 1, 1, 4, 1);
    TILE(t + 1, avB, avA, 1, 1, 4, 1);
  }
  TILE(124, avA, avB, 1, 1, 4, 1);
  TILE(125, avB, avA, 0, 1, 0, 1);
  TILE(126, avA, avB, 0, 1, -1, 0);
  TILE(127, avB, avA, 0, 0, -1, 0);

  int crow = (bm << 8) + (wm << 7) + (lg << 2);
  int ccol = (bn << 8) + (wn << 6) + lr;
#pragma unroll
  for (int i = 0; i < 8; ++i)
#pragma unroll
    for (int j = 0; j < 4; ++j)
#pragma unroll
      for (int r = 0; r < 4; ++r) {
        size_t off = (size_t)(crow + (i << 4) + r) * N + ccol + (j << 4);
        if (OUTF32) ((float*)Cv)[off] = acc[i][j][r];
        else        ((unsigned short*)Cv)[off] = bf16u(acc[i][j][r]);
      }
}

// ================= GEMM body 2: 8-phase (for GEMM2, R17) =================
// BK=64, 2 dbuf x 4 half-tiles, 4 phases/K-tile, counted vmcnt(6).
#define STAGEHT(T, OP, H) do { \
    const unsigned short* s_ = (OP) ? bS : aS; \
    char* d_ = smem + (((T) & 1) << 16) + ((OP) << 15) + ((H) << 14) + (wave << 10); \
    GLL16(s_ + ((size_t)((H) << 7)) * K + (size_t)(T) * 64, d_); \
    GLL16(s_ + ((size_t)(((H) << 7) + 64)) * K + (size_t)(T) * 64, d_ + 8192); \
  } while (0)

#define RD_AV8(RI, BUFA) do { \
    _Pragma("unroll") \
    for (int i_ = 0; i_ < 4; ++i_) { \
      av[2 * i_]     = *(const bf16x8*)((BUFA) + ((RI) << 13) + (i_ << 11) + (lr << 7) + ch0); \
      av[2 * i_ + 1] = *(const bf16x8*)((BUFA) + ((RI) << 13) + (i_ << 11) + (lr << 7) + (ch0 ^ 64)); \
    } } while (0)

#define RD_BV4(CI, BUFB, DST) do { \
    _Pragma("unroll") \
    for (int j_ = 0; j_ < 2; ++j_) { \
      DST[2 * j_]     = *(const bf16x8*)((BUFB) + ((CI) << 12) + (j_ << 11) + (lr << 7) + ch0); \
      DST[2 * j_ + 1] = *(const bf16x8*)((BUFB) + ((CI) << 12) + (j_ << 11) + (lr << 7) + (ch0 ^ 64)); \
    } } while (0)

#define MFMA16(RI, CI, BV) do { \
    _Pragma("unroll") \
    for (int i_ = 0; i_ < 4; ++i_) \
      _Pragma("unroll") \
      for (int j_ = 0; j_ < 2; ++j_) { \
        acc[(RI) * 4 + i_][(CI) * 2 + j_] = __builtin_amdgcn_mfma_f32_16x16x32_bf16(av[2 * i_],     BV[2 * j_],     acc[(RI) * 4 + i_][(CI) * 2 + j_], 0, 0, 0); \
        acc[(RI) * 4 + i_][(CI) * 2 + j_] = __builtin_amdgcn_mfma_f32_16x16x32_bf16(av[2 * i_ + 1], BV[2 * j_ + 1], acc[(RI) * 4 + i_][(CI) * 2 + j_], 0, 0, 0); \
      } } while (0)

#define TILE8(T, S1, S3, S4, VM) do { \
    char* bufA_ = smem + (((T) & 1) << 16) + (wm << 14); \
    char* bufB_ = smem + (((T) & 1) << 16) + 32768 + ((wn >> 1) << 14) + ((wn & 1) << 13); \
    RD_AV8(0, bufA_); \
    RD_BV4(0, bufB_, bv0); \
    if (S1) STAGEHT((T) + 1, 1, 1); \
    __builtin_amdgcn_s_barrier(); \
    asm volatile("s_waitcnt lgkmcnt(0)" ::: "memory"); \
    __builtin_amdgcn_s_setprio(1); MFMA16(0, 0, bv0); __builtin_amdgcn_s_setprio(0); \
    __builtin_amdgcn_s_barrier(); \
    RD_BV4(1, bufB_, bv1); \
    __builtin_amdgcn_s_barrier(); \
    asm volatile("s_waitcnt lgkmcnt(0)" ::: "memory"); \
    __builtin_amdgcn_s_setprio(1); MFMA16(0, 1, bv1); __builtin_amdgcn_s_setprio(0); \
    __builtin_amdgcn_s_barrier(); \
    RD_AV8(1, bufA_); \
    if (S3) STAGEHT((T) + 2, 1, 0); \
    __builtin_amdgcn_s_barrier(); \
    asm volatile("s_waitcnt lgkmcnt(0)" ::: "memory"); \
    __builtin_amdgcn_s_setprio(1); MFMA16(1, 0, bv0); __builtin_amdgcn_s_setprio(0); \
    __builtin_amdgcn_s_barrier(); \
    if (S4) { STAGEHT((T) + 2, 0, 0); STAGEHT((T) + 2, 0, 1); } \
    __builtin_amdgcn_s_barrier(); \
    __builtin_amdgcn_s_setprio(1); MFMA16(1, 1, bv1); __builtin_amdgcn_s_setprio(0); \
    if ((VM) == 6)      asm volatile("s_waitcnt vmcnt(6)" ::: "memory"); \
    else if ((VM) == 0) asm volatile("s_waitcnt vmcnt(0)" ::: "memory"); \
    __builtin_amdgcn_s_barrier(); \
  } while (0)

template<int OUTF32>
__global__ __launch_bounds__(512, 2)
void gemm_8p(const unsigned short* __restrict__ A, const unsigned short* __restrict__ Bt,
             void* __restrict__ Cv, int M, int N, int K) {
  __shared__ __align__(16) char smem[131072];
  const int tid = threadIdx.x;
  const int wave = tid >> 6, lane = tid & 63;
  const int lr = lane & 15, lg = lane >> 4;
  const int wm = wave >> 2, wn = wave & 3;
  const int ch0 = ((lg ^ (lr & 7)) << 4);
  const int nbn = N >> 8;
  const int nbm = M >> 8;
  int bid = blockIdx.x;
  const int bnx = nbn >> 3;
  int x = bid & 7;
  int l = bid >> 3;
  int bm = l % nbm;
  int bn = x * bnx + l / nbm;
  const size_t arow = (size_t)bm << 8;
  const size_t brow = (size_t)bn << 8;

  const int sg = lane >> 3;
  const int scolE = ((lane & 7) ^ sg) << 3;
  const unsigned short* aS = A  + (arow + (wave << 3) + sg) * (size_t)K + scolE;
  const unsigned short* bS = Bt + (brow + (wave << 3) + sg) * (size_t)K + scolE;

  f32x4 acc[8][4] = {};
  bf16x8 av[8], bv0[4], bv1[4];

  STAGEHT(0, 0, 0); STAGEHT(0, 0, 1); STAGEHT(0, 1, 0); STAGEHT(0, 1, 1);
  STAGEHT(1, 1, 0); STAGEHT(1, 0, 0); STAGEHT(1, 0, 1);
  asm volatile("s_waitcnt vmcnt(6)" ::: "memory");
  __builtin_amdgcn_s_barrier();

  for (int t = 0; t < 62; ++t) TILE8(t, 1, 1, 1, 6);
  TILE8(62, 1, 0, 0, 0);
  TILE8(63, 0, 0, 0, -1);

  int crow = (bm << 8) + (wm << 7) + (lg << 2);
  int ccol = (bn << 8) + (wn << 6) + lr;
#pragma unroll
  for (int i = 0; i < 8; ++i)
#pragma unroll
    for (int j = 0; j < 4; ++j)
#pragma unroll
      for (int r = 0; r < 4; ++r) {
        size_t off = (size_t)(crow + (i << 4) + r) * N + ccol + (j << 4);
        if (OUTF32) ((float*)Cv)[off] = acc[i][j][r];
        else        ((unsigned short*)Cv)[off] = bf16u(acc[i][j][r]);
      }
}

// ---------- causal flash attention with ALiBi (R12 proven, unchanged) ----------
__global__ __launch_bounds__(512, 2)
void attn_kernel(const unsigned short* __restrict__ qkv, unsigned short* __restrict__ out) {
  __shared__ __align__(16) unsigned short Ks[2][64 * 128];  // 32 KB, swizzled
  __shared__ __align__(16) unsigned short Vt[128 * 64];     // 16 KB [d][kk], swizzled
  __shared__ __align__(16) unsigned short Ps[8][32 * 72];   // 36 KB per-wave P, stride 72
  int tid = threadIdx.x, wave = tid >> 6, lane = tid & 63;
  int lr = lane & 15, lg = lane >> 4;
  int idx = blockIdx.x;
  int qtsel = idx & 7, h = (idx >> 3) & 31, bsel = idx >> 8;
  int qt = bsel ? qtsel : 7 - qtsel;      // complementary qt for CU pairs
  size_t rb = (size_t)bsel * PS;
  int qcol = h << 7, kcol = PH + (h << 7), vcol = 2 * PH + (h << 7);
  int q0 = (qt << 8) + (wave << 5);       // wave's 32 q-rows start

  bf16x8 aq[2][4];
#pragma unroll
  for (int qs = 0; qs < 2; ++qs)
#pragma unroll
    for (int f = 0; f < 4; ++f)
      aq[qs][f] = *(const bf16x8*)(qkv + (rb + q0 + (qs << 4) + lr) * P3H + qcol + (f << 5) + (lg << 3));

  float m_run[2][4], l_run[2][4];
#pragma unroll
  for (int qs = 0; qs < 2; ++qs)
#pragma unroll
    for (int r = 0; r < 4; ++r) { m_run[qs][r] = -1e30f; l_run[qs][r] = 0.f; }
  f32x4 acc_o[2][8] = {};

  float slope2 = __builtin_amdgcn_exp2f(-(float)(h + 1) * 0.25f) * 1.44269504f;
  const float scale2 = 0.08838834764831845f * 1.44269504f;

  char* KsB = (char*)Ks;
  char* VtB = (char*)Vt;
  const int kk0 = (tid & 31) << 1;
  const int d0 = (tid >> 5) << 3;

  {
    size_t krow = rb;
#pragma unroll
    for (int i = 0; i < 2; ++i) {
      int pf = (wave << 11) | (i << 10) | (lane << 4);
      int row = pf >> 8;
      int lch = ((pf >> 4) & 15) ^ (row & 7);
      GLL16(qkv + (krow + row) * P3H + kcol + (lch << 3), KsB + (wave << 11) + (i << 10));
    }
  }
  u32x4 vr0 = *(const u32x4*)(qkv + (rb + kk0 + 0) * P3H + vcol + d0);
  u32x4 vr1 = *(const u32x4*)(qkv + (rb + kk0 + 1) * P3H + vcol + d0);

  const int tmax = 4 * qt + 3;
  for (int t = 0; t <= tmax; ++t) {
    int cur = t & 1;
    char* KsCur = KsB + (cur << 14);
    char* KsNxt = KsB + ((cur ^ 1) << 14);
    bool more = (t < tmax);

    u32x4 nv0 = {}, nv1 = {};
    if (more) {
      size_t krow = rb + ((size_t)(t + 1) << 6);
#pragma unroll
      for (int i = 0; i < 2; ++i) {
        int pf = (wave << 11) | (i << 10) | (lane << 4);
        int row = pf >> 8;
        int lch = ((pf >> 4) & 15) ^ (row & 7);
        GLL16(qkv + (krow + row) * P3H + kcol + (lch << 3), KsNxt + (wave << 11) + (i << 10));
      }
      nv0 = *(const u32x4*)(qkv + (krow + kk0 + 0) * P3H + vcol + d0);
      nv1 = *(const u32x4*)(qkv + (krow + kk0 + 1) * P3H + vcol + d0);
    }

    if (more) asm volatile("s_waitcnt vmcnt(4)" ::: "memory");
    else      asm volatile("s_waitcnt vmcnt(0)" ::: "memory");

    {
      const unsigned short* e0 = (const unsigned short*)&vr0;
      const unsigned short* e1 = (const unsigned short*)&vr1;
#pragma unroll
      for (int j = 0; j < 8; ++j) {
        int d = d0 + j;
        unsigned int w = (unsigned int)e0[j] | ((unsigned int)e1[j] << 16);
        int byteoff = ((d << 7) + (kk0 << 1)) ^ ((d & 7) << 4);
        *(unsigned int*)(VtB + byteoff) = w;
      }
    }
    asm volatile("s_waitcnt lgkmcnt(0)" ::: "memory");
    __builtin_amdgcn_s_barrier();

    f32x4 sc[2][4];
    __builtin_amdgcn_s_setprio(1);
#pragma unroll
    for (int f = 0; f < 4; ++f) {
      f32x4 c0 = {}, c1 = {};
#pragma unroll
      for (int ks = 0; ks < 4; ++ks) {
        int kkr = (f << 4) + lr;
        int ch = (lg + (ks << 2)) ^ (kkr & 7);
        bf16x8 bk = *(const bf16x8*)(KsCur + (kkr << 8) + (ch << 4));
        c0 = __builtin_amdgcn_mfma_f32_16x16x32_bf16(aq[0][ks], bk, c0, 0, 0, 0);
        c1 = __builtin_amdgcn_mfma_f32_16x16x32_bf16(aq[1][ks], bk, c1, 0, 0, 0);
      }
      sc[0][f] = c0; sc[1][f] = c1;
    }
    __builtin_amdgcn_s_setprio(0);

    int kvb = t << 6;
    bool needmask = (kvb + 63 > q0);
#pragma unroll
    for (int qs = 0; qs < 2; ++qs) {
      float vals[4][4];
#pragma unroll
      for (int f = 0; f < 4; ++f) {
        int kv = kvb + (f << 4) + lr;
        float bias = slope2 * (float)kv;
#pragma unroll
        for (int r = 0; r < 4; ++r) {
          float v = sc[qs][f][r] * scale2 + bias;
          if (needmask && kv > q0 + (qs << 4) + (lg << 2) + r) v = -1e30f;
          vals[r][f] = v;
        }
      }
      float alpha[4];
#pragma unroll
      for (int r = 0; r < 4; ++r) {
        float mr = fmaxf(fmaxf(vals[r][0], vals[r][1]), fmaxf(vals[r][2], vals[r][3]));
#pragma unroll
        for (int d2 = 1; d2 < 16; d2 <<= 1) mr = fmaxf(mr, __shfl_xor(mr, d2, 16));
        float mnew = fmaxf(m_run[qs][r], mr);
        alpha[r] = __builtin_amdgcn_exp2f(m_run[qs][r] - mnew);
        m_run[qs][r] = mnew;
      }
#pragma unroll
      for (int r = 0; r < 4; ++r) {
        float s = 0.f;
#pragma unroll
        for (int f = 0; f < 4; ++f) {
          float p = __builtin_amdgcn_exp2f(vals[r][f] - m_run[qs][r]);
          s += p;
          Ps[wave][((qs << 4) + (lg << 2) + r) * 72 + (f << 4) + lr] = bf16u(p);
        }
        l_run[qs][r] = l_run[qs][r] * alpha[r] + s;
      }
#pragma unroll
      for (int d = 0; d < 8; ++d) {
        f32x4 a4 = acc_o[qs][d];
#pragma unroll
        for (int r = 0; r < 4; ++r) a4[r] *= alpha[r];
        acc_o[qs][d] = a4;
      }
    }

    bf16x8 pa[2][2];
#pragma unroll
    for (int qs = 0; qs < 2; ++qs)
#pragma unroll
      for (int ks = 0; ks < 2; ++ks)
        pa[qs][ks] = *(const bf16x8*)((char*)&Ps[wave][0] + ((qs << 4) + lr) * 144 + (ks << 6) + (lg << 4));
    __builtin_amdgcn_s_setprio(1);
#pragma unroll
    for (int d = 0; d < 8; ++d) {
#pragma unroll
      for (int ks = 0; ks < 2; ++ks) {
        int dr = (d << 4) + lr;
        int ch = (lg + (ks << 2)) ^ (dr & 7);
        bf16x8 bv = *(const bf16x8*)(VtB + (dr << 7) + (ch << 4));
        acc_o[0][d] = __builtin_amdgcn_mfma_f32_16x16x32_bf16(pa[0][ks], bv, acc_o[0][d], 0, 0, 0);
        acc_o[1][d] = __builtin_amdgcn_mfma_f32_16x16x32_bf16(pa[1][ks], bv, acc_o[1][d], 0, 0, 0);
      }
    }
    __builtin_amdgcn_s_setprio(0);
    __builtin_amdgcn_s_barrier();

    if (more) { vr0 = nv0; vr1 = nv1; }
  }

#pragma unroll
  for (int qs = 0; qs < 2; ++qs) {
    float rinv[4];
#pragma unroll
    for (int r = 0; r < 4; ++r) {
      float s = l_run[qs][r];
#pragma unroll
      for (int d2 = 1; d2 < 16; d2 <<= 1) s += __shfl_xor(s, d2, 16);
      rinv[r] = 1.f / s;
    }
#pragma unroll
    for (int d = 0; d < 8; ++d)
#pragma unroll
      for (int r = 0; r < 4; ++r) {
        float o = acc_o[qs][d][r] * rinv[r];
        out[(rb + q0 + (qs << 4) + (lg << 2) + r) * PH + (h << 7) + (d << 4) + lr] = bf16u(o);
      }
  }
}

// ---------- launcher ----------
extern "C" void kernel_launch(void* const* d_in, const int* in_sizes, int n_in,
                              void* d_out, int out_size, void* d_ws, size_t ws_size,
                              hipStream_t stream) {
  const float* hidden = (const float*)d_in[0];
  const float* w_pack = (const float*)d_in[1];
  const float* o_proj = (const float*)d_in[2];
  // k_cache/v_cache/block_offsets: scatter-then-gather with unique arange
  // offsets is the identity; caches are write-only w.r.t. the output.

  char* ws = (char*)d_ws;
  unsigned short* wpackT = (unsigned short*)(ws);                   // 96 MB [12288][4096]
  unsigned short* qkv    = (unsigned short*)(ws + 100663296);       // 96 MB [4096][12288]
  unsigned short* oprojT = (unsigned short*)(ws + 201326592);       // 32 MB [4096][4096]
  unsigned short* hbf    = (unsigned short*)(ws + 234881024);       // 32 MB
  unsigned short* attnb  = hbf;  // hidden_bf16 dead after GEMM1; reuse

  int M = PB * PS;  // 4096 tokens

  cvt_f32_bf16<<<2048, 256, 0, stream>>>(hidden, hbf, M * PH);
  transpose_cvt<<<dim3(P3H / 64, PH / 64), 256, 0, stream>>>(w_pack, wpackT, PH, P3H);
  transpose_cvt<<<dim3(PH / 64, PH / 64), 256, 0, stream>>>(o_proj, oprojT, PH, PH);
  gemm_r14<0><<<(M / 256) * (P3H / 256), 512, 0, stream>>>(hbf, wpackT, qkv, M, P3H, PH);
  attn_kernel<<<PB * PNH * (PS / 256), 512, 0, stream>>>(qkv, attnb);
  gemm_8p<1><<<(M / 256) * (PH / 256), 512, 0, stream>>>(attnb, oprojT, d_out, M, PH, PH);
}

// Round 19
// 710.050 us; speedup vs baseline: 1.0387x; 1.0387x over previous
//
#include <hip/hip_runtime.h>
#include <hip/hip_bf16.h>
#include <stdint.h>

// ---------- types ----------
typedef __attribute__((ext_vector_type(4))) float f32x4;
typedef __attribute__((ext_vector_type(8))) __bf16 bf16x8;
typedef __attribute__((ext_vector_type(8))) unsigned short u16x8;
typedef __attribute__((ext_vector_type(4))) unsigned short u16x4;
typedef __attribute__((ext_vector_type(4))) unsigned int u32x4;

// global_load_lds, 16B per lane. LDS dest must be wave-uniform (HW adds lane*16).
#define GLL16(g, l) __builtin_amdgcn_global_load_lds( \
    (const __attribute__((address_space(1))) unsigned int*)(uintptr_t)(g), \
    (__attribute__((address_space(3))) unsigned int*)(uintptr_t)(l), 16, 0, 0)

__device__ __forceinline__ unsigned short bf16u(float f) {
  return __builtin_bit_cast(unsigned short, __float2bfloat16(f));
}

// ---------- problem constants ----------
#define PB 2
#define PS 2048
#define PNH 32
#define PHD 128
#define PH 4096
#define P3H 12288

// ---------- fp32 -> bf16 convert (vectorized, grid-stride) ----------
__global__ __launch_bounds__(256)
void cvt_f32_bf16(const float* __restrict__ in, unsigned short* __restrict__ out, int n) {
  int stride = gridDim.x * blockDim.x;
  for (int i = blockIdx.x * blockDim.x + threadIdx.x; i * 8 < n; i += stride) {
    int base = i * 8;
    f32x4 a = *(const f32x4*)(in + base);
    f32x4 b = *(const f32x4*)(in + base + 4);
    u16x8 o;
#pragma unroll
    for (int j = 0; j < 4; ++j) { o[j] = bf16u(a[j]); o[4 + j] = bf16u(b[j]); }
    *(u16x8*)(out + base) = o;
  }
}

// ---------- transpose + convert: in[K][N] f32 -> out[N][K] bf16 ----------
__global__ __launch_bounds__(256)
void transpose_cvt(const float* __restrict__ in, unsigned short* __restrict__ out,
                   int K, int N) {
  __shared__ __align__(16) unsigned short tile[64][68];
  int k0 = blockIdx.y * 64, n0 = blockIdx.x * 64;
  int t = threadIdx.x;
  int rr = t >> 4, cc = (t & 15) * 4;
#pragma unroll
  for (int p = 0; p < 4; ++p) {
    int r = rr + p * 16;
    f32x4 v = *(const f32x4*)(in + (size_t)(k0 + r) * N + n0 + cc);
    u16x4 w;
#pragma unroll
    for (int j = 0; j < 4; ++j) w[j] = bf16u(v[j]);
    *(u16x4*)&tile[r][cc] = w;
  }
  __syncthreads();
#pragma unroll
  for (int p = 0; p < 4; ++p) {
    int nl = rr + p * 16;
    u16x4 w;
#pragma unroll
    for (int j = 0; j < 4; ++j) w[j] = tile[cc + j][nl];
    *(u16x4*)(out + (size_t)(n0 + nl) * K + k0 + cc) = w;
  }
}

// ---------- 256x256-tile bf16 GEMM, 8-phase schedule (R17, best measured) ----------
// K MUST be 4096 (NT=64 K-tiles of BK=64, hardcoded tail).
// m201-template port: 8 waves (2M x 4N), per-wave 128x64. BK=64; LDS =
// 2 dbuf x {A0,A1,B0,B1 half-tiles of 128x64} = 128 KB. Per K-tile, 4 phases
// (one C-quadrant x K=64 each, 16 MFMA):
//   P1(r0,c0): read av(r0) 8xb128 + bv0 4xb128; stage B1(t+1)
//   P2(r0,c1): read bv1;                         no stage
//   P3(r1,c0): read av(r1);                      stage B0(t+2)
//   P4(r1,c1): no reads;                         stage A0,A1(t+2); vmcnt(6)
// Each phase: {reads/stage; barrier; lgkmcnt(0); setprio(1); 16 MFMA;
// setprio(0); barrier}. vmcnt(6) = 2 loads/HT x 3 HTs in flight; end-of-tile
// drain = exactly tile t+1. Same-buffer staging (t+2 -> cur) race-free:
// B-reads complete by P2's post-MFMA barrier, A-reads by P3's.
// NOTE (R17/R18 A/B): this body is ~27us FASTER than the R14 2-barrier body
// on GEMM1 in timed graph-replay, though rocprof replay inflates its
// profiled duration (383 vs ~325 timed) -- trust the timed total.
// Swizzle: read chunk = (kk*4+lg)^(lr&7); GLL source col = ((lane&7)^(lane>>3))*8
// (matching involution, GLL dest linear, rule #21). bn-major XCD chunking.
#define STAGEHT(T, OP, H) do { \
    const unsigned short* s_ = (OP) ? bS : aS; \
    char* d_ = smem + (((T) & 1) << 16) + ((OP) << 15) + ((H) << 14) + (wave << 10); \
    GLL16(s_ + ((size_t)((H) << 7)) * K + (size_t)(T) * 64, d_); \
    GLL16(s_ + ((size_t)(((H) << 7) + 64)) * K + (size_t)(T) * 64, d_ + 8192); \
  } while (0)

#define RD_AV8(RI, BUFA) do { \
    _Pragma("unroll") \
    for (int i_ = 0; i_ < 4; ++i_) { \
      av[2 * i_]     = *(const bf16x8*)((BUFA) + ((RI) << 13) + (i_ << 11) + (lr << 7) + ch0); \
      av[2 * i_ + 1] = *(const bf16x8*)((BUFA) + ((RI) << 13) + (i_ << 11) + (lr << 7) + (ch0 ^ 64)); \
    } } while (0)

#define RD_BV4(CI, BUFB, DST) do { \
    _Pragma("unroll") \
    for (int j_ = 0; j_ < 2; ++j_) { \
      DST[2 * j_]     = *(const bf16x8*)((BUFB) + ((CI) << 12) + (j_ << 11) + (lr << 7) + ch0); \
      DST[2 * j_ + 1] = *(const bf16x8*)((BUFB) + ((CI) << 12) + (j_ << 11) + (lr << 7) + (ch0 ^ 64)); \
    } } while (0)

#define MFMA16(RI, CI, BV) do { \
    _Pragma("unroll") \
    for (int i_ = 0; i_ < 4; ++i_) \
      _Pragma("unroll") \
      for (int j_ = 0; j_ < 2; ++j_) { \
        acc[(RI) * 4 + i_][(CI) * 2 + j_] = __builtin_amdgcn_mfma_f32_16x16x32_bf16(av[2 * i_],     BV[2 * j_],     acc[(RI) * 4 + i_][(CI) * 2 + j_], 0, 0, 0); \
        acc[(RI) * 4 + i_][(CI) * 2 + j_] = __builtin_amdgcn_mfma_f32_16x16x32_bf16(av[2 * i_ + 1], BV[2 * j_ + 1], acc[(RI) * 4 + i_][(CI) * 2 + j_], 0, 0, 0); \
      } } while (0)

#define TILE8(T, S1, S3, S4, VM) do { \
    char* bufA_ = smem + (((T) & 1) << 16) + (wm << 14); \
    char* bufB_ = smem + (((T) & 1) << 16) + 32768 + ((wn >> 1) << 14) + ((wn & 1) << 13); \
    /* P1 (r0,c0) */ \
    RD_AV8(0, bufA_); \
    RD_BV4(0, bufB_, bv0); \
    if (S1) STAGEHT((T) + 1, 1, 1); \
    __builtin_amdgcn_s_barrier(); \
    asm volatile("s_waitcnt lgkmcnt(0)" ::: "memory"); \
    __builtin_amdgcn_s_setprio(1); MFMA16(0, 0, bv0); __builtin_amdgcn_s_setprio(0); \
    __builtin_amdgcn_s_barrier(); \
    /* P2 (r0,c1) */ \
    RD_BV4(1, bufB_, bv1); \
    __builtin_amdgcn_s_barrier(); \
    asm volatile("s_waitcnt lgkmcnt(0)" ::: "memory"); \
    __builtin_amdgcn_s_setprio(1); MFMA16(0, 1, bv1); __builtin_amdgcn_s_setprio(0); \
    __builtin_amdgcn_s_barrier(); \
    /* P3 (r1,c0) */ \
    RD_AV8(1, bufA_); \
    if (S3) STAGEHT((T) + 2, 1, 0); \
    __builtin_amdgcn_s_barrier(); \
    asm volatile("s_waitcnt lgkmcnt(0)" ::: "memory"); \
    __builtin_amdgcn_s_setprio(1); MFMA16(1, 0, bv0); __builtin_amdgcn_s_setprio(0); \
    __builtin_amdgcn_s_barrier(); \
    /* P4 (r1,c1) */ \
    if (S4) { STAGEHT((T) + 2, 0, 0); STAGEHT((T) + 2, 0, 1); } \
    __builtin_amdgcn_s_barrier(); \
    __builtin_amdgcn_s_setprio(1); MFMA16(1, 1, bv1); __builtin_amdgcn_s_setprio(0); \
    if ((VM) == 6)      asm volatile("s_waitcnt vmcnt(6)" ::: "memory"); \
    else if ((VM) == 0) asm volatile("s_waitcnt vmcnt(0)" ::: "memory"); \
    __builtin_amdgcn_s_barrier(); \
  } while (0)

template<int OUTF32>
__global__ __launch_bounds__(512, 2)
void gemm256(const unsigned short* __restrict__ A, const unsigned short* __restrict__ Bt,
             void* __restrict__ Cv, int M, int N, int K) {
  __shared__ __align__(16) char smem[131072];  // 2 buffers x 64 KB (A0,A1,B0,B1)
  const int tid = threadIdx.x;
  const int wave = tid >> 6, lane = tid & 63;
  const int lr = lane & 15, lg = lane >> 4;
  const int wm = wave >> 2, wn = wave & 3;
  const int ch0 = ((lg ^ (lr & 7)) << 4);  // kk=0 chunk byte; kk=1 = ch0^64
  const int nbn = N >> 8;                 // 48 (GEMM1) or 16 (GEMM2)
  const int nbm = M >> 8;                 // 16
  int bid = blockIdx.x;
  // bn-major XCD chunking: XCD x = bid&7 owns bn-cols [x*bnx,(x+1)*bnx),
  // bm-fastest within the strip -> live B-panels L2-resident per XCD.
  const int bnx = nbn >> 3;
  int x = bid & 7;
  int l = bid >> 3;
  int bm = l % nbm;
  int bn = x * bnx + l / nbm;
  const size_t arow = (size_t)bm << 8;
  const size_t brow = (size_t)bn << 8;

  // staging source: GLL g of half-tile covers LDS byte g*8192 + wave*1024 +
  // lane*16 -> src row (within 128-row half) = g*64 + wave*8 + (lane>>3),
  // src col chunk = (lane&7) ^ (lane>>3)  (pre-swizzled involution).
  const int sg = lane >> 3;
  const int scolE = ((lane & 7) ^ sg) << 3;
  const unsigned short* aS = A  + (arow + (wave << 3) + sg) * (size_t)K + scolE;
  const unsigned short* bS = Bt + (brow + (wave << 3) + sg) * (size_t)K + scolE;

  f32x4 acc[8][4] = {};
  bf16x8 av[8], bv0[4], bv1[4];

  // prologue: stage t0 {A0,A1,B0,B1} + t1 {B0,A0,A1}; vmcnt(6) -> t0 landed.
  STAGEHT(0, 0, 0); STAGEHT(0, 0, 1); STAGEHT(0, 1, 0); STAGEHT(0, 1, 1);
  STAGEHT(1, 1, 0); STAGEHT(1, 0, 0); STAGEHT(1, 0, 1);
  asm volatile("s_waitcnt vmcnt(6)" ::: "memory");
  __builtin_amdgcn_s_barrier();

  // NT = 64 K-tiles (K=4096, BK=64). Steady: tile t stages B1(t+1) @P1,
  // B0(t+2) @P3, A0+A1(t+2) @P4; end vmcnt(6) drains tile t+1 exactly.
  for (int t = 0; t < 62; ++t) TILE8(t, 1, 1, 1, 6);
  TILE8(62, 1, 0, 0, 0);
  TILE8(63, 0, 0, 0, -1);

  // epilogue: C layout col=lane&15, row=(lane>>4)*4+r  [m89-verified]
  int crow = (bm << 8) + (wm << 7) + (lg << 2);
  int ccol = (bn << 8) + (wn << 6) + lr;
#pragma unroll
  for (int i = 0; i < 8; ++i)
#pragma unroll
    for (int j = 0; j < 4; ++j)
#pragma unroll
      for (int r = 0; r < 4; ++r) {
        size_t off = (size_t)(crow + (i << 4) + r) * N + ccol + (j << 4);
        if (OUTF32) ((float*)Cv)[off] = acc[i][j][r];
        else        ((unsigned short*)Cv)[off] = bf16u(acc[i][j][r]);
      }
}

// ---------- causal flash attention with ALiBi (R12 proven, unchanged) ----------
// QBLK=256 (8 waves x 32 q, 512 threads), KVBLK=64; Ps stride 72 shorts.
// LDS 84 KB -> 1 block/CU x 8 waves. K dbuf GLL one tile ahead, V
// global->reg one tile ahead + late ds_write, counted vmcnt(4), raw barriers.
__global__ __launch_bounds__(512, 2)
void attn_kernel(const unsigned short* __restrict__ qkv, unsigned short* __restrict__ out) {
  __shared__ __align__(16) unsigned short Ks[2][64 * 128];  // 32 KB, swizzled
  __shared__ __align__(16) unsigned short Vt[128 * 64];     // 16 KB [d][kk], swizzled
  __shared__ __align__(16) unsigned short Ps[8][32 * 72];   // 36 KB per-wave P, stride 72
  int tid = threadIdx.x, wave = tid >> 6, lane = tid & 63;
  int lr = lane & 15, lg = lane >> 4;
  int idx = blockIdx.x;
  int qtsel = idx & 7, h = (idx >> 3) & 31, bsel = idx >> 8;
  int qt = bsel ? qtsel : 7 - qtsel;      // complementary qt for CU pairs
  size_t rb = (size_t)bsel * PS;
  int qcol = h << 7, kcol = PH + (h << 7), vcol = 2 * PH + (h << 7);
  int q0 = (qt << 8) + (wave << 5);       // wave's 32 q-rows start

  // Q fragments in registers: qs in {0,1} 16-row subtiles
  bf16x8 aq[2][4];
#pragma unroll
  for (int qs = 0; qs < 2; ++qs)
#pragma unroll
    for (int f = 0; f < 4; ++f)
      aq[qs][f] = *(const bf16x8*)(qkv + (rb + q0 + (qs << 4) + lr) * P3H + qcol + (f << 5) + (lg << 3));

  float m_run[2][4], l_run[2][4];
#pragma unroll
  for (int qs = 0; qs < 2; ++qs)
#pragma unroll
    for (int r = 0; r < 4; ++r) { m_run[qs][r] = -1e30f; l_run[qs][r] = 0.f; }
  f32x4 acc_o[2][8] = {};

  float slope2 = __builtin_amdgcn_exp2f(-(float)(h + 1) * 0.25f) * 1.44269504f;
  const float scale2 = 0.08838834764831845f * 1.44269504f;

  char* KsB = (char*)Ks;
  char* VtB = (char*)Vt;
  const int kk0 = (tid & 31) << 1;        // 2 kv rows per thread
  const int d0 = (tid >> 5) << 3;         // 8 d per thread (tid>>5 in 0..15)

  // ---- prologue: issue K(0) GLL -> Ks[0] (2 ops), V(0) global->reg (2 ops) ----
  {
    size_t krow = rb;
#pragma unroll
    for (int i = 0; i < 2; ++i) {
      int pf = (wave << 11) | (i << 10) | (lane << 4);
      int row = pf >> 8;
      int lch = ((pf >> 4) & 15) ^ (row & 7);
      GLL16(qkv + (krow + row) * P3H + kcol + (lch << 3), KsB + (wave << 11) + (i << 10));
    }
  }
  u32x4 vr0 = *(const u32x4*)(qkv + (rb + kk0 + 0) * P3H + vcol + d0);
  u32x4 vr1 = *(const u32x4*)(qkv + (rb + kk0 + 1) * P3H + vcol + d0);

  const int tmax = 4 * qt + 3;            // 64-kv tiles 0..tmax (kv up to 256*(qt+1))
  for (int t = 0; t <= tmax; ++t) {
    int cur = t & 1;
    char* KsCur = KsB + (cur << 14);
    char* KsNxt = KsB + ((cur ^ 1) << 14);
    bool more = (t < tmax);

    // ---- issue next tile's loads (4 vmem ops) ----
    u32x4 nv0 = {}, nv1 = {};
    if (more) {
      size_t krow = rb + ((size_t)(t + 1) << 6);
#pragma unroll
      for (int i = 0; i < 2; ++i) {
        int pf = (wave << 11) | (i << 10) | (lane << 4);
        int row = pf >> 8;
        int lch = ((pf >> 4) & 15) ^ (row & 7);
        GLL16(qkv + (krow + row) * P3H + kcol + (lch << 3), KsNxt + (wave << 11) + (i << 10));
      }
      nv0 = *(const u32x4*)(qkv + (krow + kk0 + 0) * P3H + vcol + d0);
      nv1 = *(const u32x4*)(qkv + (krow + kk0 + 1) * P3H + vcol + d0);
    }

    // ---- wait K(t)+V(t) landed; t+1's 4 ops stay in flight ----
    if (more) asm volatile("s_waitcnt vmcnt(4)" ::: "memory");
    else      asm volatile("s_waitcnt vmcnt(0)" ::: "memory");

    // ---- late ds_write of V(t) -> Vt (swizzled, u32 = 2 kv per write) ----
    {
      const unsigned short* e0 = (const unsigned short*)&vr0;
      const unsigned short* e1 = (const unsigned short*)&vr1;
#pragma unroll
      for (int j = 0; j < 8; ++j) {
        int d = d0 + j;
        unsigned int w = (unsigned int)e0[j] | ((unsigned int)e1[j] << 16);
        int byteoff = ((d << 7) + (kk0 << 1)) ^ ((d & 7) << 4);
        *(unsigned int*)(VtB + byteoff) = w;
      }
    }
    asm volatile("s_waitcnt lgkmcnt(0)" ::: "memory");
    __builtin_amdgcn_s_barrier();

    // ---- QK^T: S[32q x 64kv] per wave; K frags read once, used by both qs ----
    f32x4 sc[2][4];
    __builtin_amdgcn_s_setprio(1);
#pragma unroll
    for (int f = 0; f < 4; ++f) {
      f32x4 c0 = {}, c1 = {};
#pragma unroll
      for (int ks = 0; ks < 4; ++ks) {
        int kkr = (f << 4) + lr;
        int ch = (lg + (ks << 2)) ^ (kkr & 7);
        bf16x8 bk = *(const bf16x8*)(KsCur + (kkr << 8) + (ch << 4));
        c0 = __builtin_amdgcn_mfma_f32_16x16x32_bf16(aq[0][ks], bk, c0, 0, 0, 0);
        c1 = __builtin_amdgcn_mfma_f32_16x16x32_bf16(aq[1][ks], bk, c1, 0, 0, 0);
      }
      sc[0][f] = c0; sc[1][f] = c1;
    }
    __builtin_amdgcn_s_setprio(0);

    // ---- online softmax per qs (exp2 domain) ----
    int kvb = t << 6;
    bool needmask = (kvb + 63 > q0);      // wave-level causal gate
#pragma unroll
    for (int qs = 0; qs < 2; ++qs) {
      float vals[4][4];
#pragma unroll
      for (int f = 0; f < 4; ++f) {
        int kv = kvb + (f << 4) + lr;
        float bias = slope2 * (float)kv;
#pragma unroll
        for (int r = 0; r < 4; ++r) {
          float v = sc[qs][f][r] * scale2 + bias;
          if (needmask && kv > q0 + (qs << 4) + (lg << 2) + r) v = -1e30f;
          vals[r][f] = v;
        }
      }
      float alpha[4];
#pragma unroll
      for (int r = 0; r < 4; ++r) {
        float mr = fmaxf(fmaxf(vals[r][0], vals[r][1]), fmaxf(vals[r][2], vals[r][3]));
#pragma unroll
        for (int d2 = 1; d2 < 16; d2 <<= 1) mr = fmaxf(mr, __shfl_xor(mr, d2, 16));
        float mnew = fmaxf(m_run[qs][r], mr);
        alpha[r] = __builtin_amdgcn_exp2f(m_run[qs][r] - mnew);
        m_run[qs][r] = mnew;
      }
#pragma unroll
      for (int r = 0; r < 4; ++r) {
        float s = 0.f;
#pragma unroll
        for (int f = 0; f < 4; ++f) {
          float p = __builtin_amdgcn_exp2f(vals[r][f] - m_run[qs][r]);
          s += p;
          Ps[wave][((qs << 4) + (lg << 2) + r) * 72 + (f << 4) + lr] = bf16u(p);
        }
        l_run[qs][r] = l_run[qs][r] * alpha[r] + s;   // lane-partial; reduced at end
      }
#pragma unroll
      for (int d = 0; d < 8; ++d) {
        f32x4 a4 = acc_o[qs][d];
#pragma unroll
        for (int r = 0; r < 4; ++r) a4[r] *= alpha[r];
        acc_o[qs][d] = a4;
      }
    }

    // ---- PV: O[32q x 128d] += P[32x64] @ V[64x128]; V frags shared by qs ----
    // Ps rows stride 72 shorts = 144 B = 9x16 (b128-aligned); pa row = qs*16+lr.
    bf16x8 pa[2][2];
#pragma unroll
    for (int qs = 0; qs < 2; ++qs)
#pragma unroll
      for (int ks = 0; ks < 2; ++ks)
        pa[qs][ks] = *(const bf16x8*)((char*)&Ps[wave][0] + ((qs << 4) + lr) * 144 + (ks << 6) + (lg << 4));
    __builtin_amdgcn_s_setprio(1);
#pragma unroll
    for (int d = 0; d < 8; ++d) {
#pragma unroll
      for (int ks = 0; ks < 2; ++ks) {
        int dr = (d << 4) + lr;
        int ch = (lg + (ks << 2)) ^ (dr & 7);
        bf16x8 bv = *(const bf16x8*)(VtB + (dr << 7) + (ch << 4));
        acc_o[0][d] = __builtin_amdgcn_mfma_f32_16x16x32_bf16(pa[0][ks], bv, acc_o[0][d], 0, 0, 0);
        acc_o[1][d] = __builtin_amdgcn_mfma_f32_16x16x32_bf16(pa[1][ks], bv, acc_o[1][d], 0, 0, 0);
      }
    }
    __builtin_amdgcn_s_setprio(0);
    __builtin_amdgcn_s_barrier();   // protects Vt rewrite + Ks[cur] GLL next iters

    if (more) { vr0 = nv0; vr1 = nv1; }
  }

  // ---- epilogue: reduce l across 16-lane group, normalize, store bf16 ----
#pragma unroll
  for (int qs = 0; qs < 2; ++qs) {
    float rinv[4];
#pragma unroll
    for (int r = 0; r < 4; ++r) {
      float s = l_run[qs][r];
#pragma unroll
      for (int d2 = 1; d2 < 16; d2 <<= 1) s += __shfl_xor(s, d2, 16);
      rinv[r] = 1.f / s;
    }
#pragma unroll
    for (int d = 0; d < 8; ++d)
#pragma unroll
      for (int r = 0; r < 4; ++r) {
        float o = acc_o[qs][d][r] * rinv[r];
        out[(rb + q0 + (qs << 4) + (lg << 2) + r) * PH + (h << 7) + (d << 4) + lr] = bf16u(o);
      }
  }
}

// ---------- launcher ----------
extern "C" void kernel_launch(void* const* d_in, const int* in_sizes, int n_in,
                              void* d_out, int out_size, void* d_ws, size_t ws_size,
                              hipStream_t stream) {
  const float* hidden = (const float*)d_in[0];
  const float* w_pack = (const float*)d_in[1];
  const float* o_proj = (const float*)d_in[2];
  // k_cache/v_cache/block_offsets: scatter-then-gather with unique arange
  // offsets is the identity; caches are write-only w.r.t. the output.

  char* ws = (char*)d_ws;
  unsigned short* wpackT = (unsigned short*)(ws);                   // 96 MB [12288][4096]
  unsigned short* qkv    = (unsigned short*)(ws + 100663296);       // 96 MB [4096][12288]
  unsigned short* oprojT = (unsigned short*)(ws + 201326592);       // 32 MB [4096][4096]
  unsigned short* hbf    = (unsigned short*)(ws + 234881024);       // 32 MB
  unsigned short* attnb  = hbf;  // hidden_bf16 dead after GEMM1; reuse

  int M = PB * PS;  // 4096 tokens

  cvt_f32_bf16<<<2048, 256, 0, stream>>>(hidden, hbf, M * PH);
  transpose_cvt<<<dim3(P3H / 64, PH / 64), 256, 0, stream>>>(w_pack, wpackT, PH, P3H);
  transpose_cvt<<<dim3(PH / 64, PH / 64), 256, 0, stream>>>(o_proj, oprojT, PH, PH);
  gemm256<0><<<(M / 256) * (P3H / 256), 512, 0, stream>>>(hbf, wpackT, qkv, M, P3H, PH);
  attn_kernel<<<PB * PNH * (PS / 256), 512, 0, stream>>>(qkv, attnb);
  gemm256<1><<<(M / 256) * (PH / 256), 512, 0, stream>>>(attnb, oprojT, d_out, M, PH, PH);
}